// Round 4
// baseline (113.085 us; speedup 1.0000x reference)
//
#include <hip/hip_runtime.h>

#define BB 8
#define CC 64
#define NNN 4096
#define KK 20
#define MM 8
#define OC 64
#define CM 512
#define PTS 32          // points per block
#define AST 516         // aggA row stride in shorts (512 + 4 pad; 258 words = 2 mod 32)

typedef __attribute__((ext_vector_type(8))) short bf16x8;
typedef __attribute__((ext_vector_type(4))) float f32x4;

__device__ __forceinline__ unsigned short f2bf(float f) {
    union { float f; unsigned int u; } v; v.f = f;
    unsigned int u = v.u;
    return (unsigned short)((u + 0x7FFFu + ((u >> 16) & 1u)) >> 16);
}
__device__ __forceinline__ float bfhi2f(unsigned int u) {
    union { unsigned int u; float f; } v; v.u = u & 0xffff0000u; return v.f;
}
__device__ __forceinline__ float bflo2f(unsigned int u) {
    union { unsigned int u; float f; } v; v.u = u << 16; return v.f;
}

// Kernel 1: transpose feature (B,C,N)->(B,N,C) bf16 into ws; conv_w -> bf16 [o][k]
__global__ __launch_bounds__(256) void prep_kernel(const float* __restrict__ feature,
                                                   const float* __restrict__ conv_w,
                                                   unsigned short* __restrict__ ftr,
                                                   unsigned short* __restrict__ Wb) {
    int blk = blockIdx.x;
    int t = threadIdx.x;
    if (blk < 512) {
        __shared__ float tile[64 * 65];
        int b = blk & 7;
        int n0 = (blk >> 3) << 6;
        const float* fb = feature + b * (CC * NNN);
        #pragma unroll
        for (int s = 0; s < 16; ++s) {
            int i = t + s * 256;
            int c = i >> 6, nn = i & 63;
            tile[c * 65 + nn] = fb[c * NNN + n0 + nn];
        }
        __syncthreads();
        unsigned short* fo = ftr + b * (NNN * CC) + n0 * CC;
        #pragma unroll
        for (int s = 0; s < 16; ++s) {
            int i = t + s * 256;
            int n = i >> 6, cc = i & 63;
            fo[n * CC + cc] = f2bf(tile[cc * 65 + n]);
        }
    } else {
        int base = (blk - 512) * 8192;
        #pragma unroll
        for (int s = 0; s < 32; ++s) {
            int i = base + t + s * 256;
            Wb[i] = f2bf(conv_w[i]);
        }
    }
}

// Kernel 2: 32 points/block, 4 barriers, gathers issued at block start.
__global__ __launch_bounds__(256, 3) void main_kernel(
    const float* __restrict__ x,
    const float* __restrict__ feature,
    const int* __restrict__ nidx,
    const float* __restrict__ kern,
    const float* __restrict__ conv_b,
    const unsigned short* __restrict__ ftr,
    const unsigned short* __restrict__ Wb,
    float* __restrict__ out)
{
    // aggA overlays {xn, perm}: both dead before aggA is written (barrier 3)
    __shared__ __align__(16) union {
        struct {
            float xn[PTS * 60];            // 7680 B
            float perm[PTS * KK * 10];     // 25600 B (stride 10 -> 2-way writes = free)
        } s;
        unsigned short aggA[PTS * AST];    // 33024 B
    } u;

    int t = threadIdx.x;
    int blk = blockIdx.x;
    int b = blk & 7;                       // XCD-affinity swizzle
    int n0 = (blk >> 3) << 5;              // 32 points per block
    int w = t >> 6, l = t & 63;

    const int* nb = nidx + (b * NNN + n0) * KK;
    const float* xb = x + b * (3 * NNN);
    const unsigned short* fb = ftr + (size_t)b * (NNN * CC);

    // ---- phase-B / epilogue identities ----
    int p0 = t >> 4;                       // 0..15
    int p1 = p0 + 16;                      // 16..31
    int cq = (t & 15) << 2;                // channel-quad base
    int o = (w << 4) + (l & 15);           // output channel (phase C)
    int q = l >> 4;                        // point sub-quad (phase C)

    // ---- issue everything independent FIRST (all latency overlaps) ----
    // epilogue residual + bias
    float4 fres0 = *(const float4*)(feature + ((size_t)b * CC + o) * NNN + n0 + q * 4);
    float4 fres1 = *(const float4*)(feature + ((size_t)b * CC + o) * NNN + n0 + 16 + q * 4);
    float bias = conv_b[o];
    // phase-A kernel weights (thread = (pA, m))
    int mA = t & 7;
    float kw0 = kern[mA], kw1 = kern[MM + mA], kw2 = kern[2 * MM + mA];

    // point-0 indices (broadcast int4 loads) then ftr gathers, at cycle ~0
    int id0[KK];
    {
        const int4* nb4 = (const int4*)(nb + p0 * KK);
        #pragma unroll
        for (int s = 0; s < 5; ++s) {
            int4 v = nb4[s];
            id0[s * 4 + 0] = v.x; id0[s * 4 + 1] = v.y;
            id0[s * 4 + 2] = v.z; id0[s * 4 + 3] = v.w;
        }
    }
    uint2 fr0[KK];
    #pragma unroll
    for (int k = 0; k < KK; ++k)
        fr0[k] = *(const uint2*)(fb + (size_t)id0[k] * CC + cq);

    // xyz staging: 1920 slots, direct idx loads (no idx LDS, no extra barrier)
    #pragma unroll
    for (int s = 0; s < 8; ++s) {
        int i = t + s * 256;
        if (i < PTS * 60) {
            int p = i / 60;
            int rem = i - p * 60;
            int k = rem / 3;
            int c = rem - k * 3;
            int idv = nb[p * KK + k];
            u.s.xn[i] = xb[c * NNN + idv];
        }
    }
    __syncthreads();   // B1: xn ready (fr0 also landed in regs)

    // ---- phase A: softmax, thread = (pA = t>>3, m = t&7), all 256 active ----
    {
        int pA = t >> 3;
        const float* xp = &u.s.xn[pA * 60];
        float bx = xp[0], by = xp[1], bz = xp[2];
        float pv[KK];
        #pragma unroll
        for (int k = 0; k < KK; ++k) {
            float dx = xp[k * 3 + 0] - bx;
            float dy = xp[k * 3 + 1] - by;
            float dz = xp[k * 3 + 2] - bz;
            pv[k] = dx * kw0 + dy * kw1 + dz * kw2;
        }
        if (mA == 0) pv[0] += 1.0f;        // one_pad[0,0]
        float mx = pv[0];
        #pragma unroll
        for (int k = 1; k < KK; ++k) mx = fmaxf(mx, pv[k]);
        float sum = 0.f;
        #pragma unroll
        for (int k = 0; k < KK; ++k) { pv[k] = __expf(pv[k] - mx); sum += pv[k]; }
        float inv = 1.0f / sum;
        #pragma unroll
        for (int k = 0; k < KK; ++k) u.s.perm[(pA * KK + k) * 10 + mA] = pv[k] * inv;
    }
    __syncthreads();   // B2: perm ready

    // ---- phase B: agg for p0 (regs ready) and p1 (issue now, consume after) ----
    int id1[KK];
    {
        const int4* nb4 = (const int4*)(nb + p1 * KK);
        #pragma unroll
        for (int s = 0; s < 5; ++s) {
            int4 v = nb4[s];
            id1[s * 4 + 0] = v.x; id1[s * 4 + 1] = v.y;
            id1[s * 4 + 2] = v.z; id1[s * 4 + 3] = v.w;
        }
    }
    uint2 fr1[KK];
    #pragma unroll
    for (int k = 0; k < KK; ++k)
        fr1[k] = *(const uint2*)(fb + (size_t)id1[k] * CC + cq);

    float acc0[4][MM], acc1[4][MM];
    #pragma unroll
    for (int ci = 0; ci < 4; ++ci)
        #pragma unroll
        for (int m = 0; m < MM; ++m) { acc0[ci][m] = 0.f; acc1[ci][m] = 0.f; }

    #pragma unroll
    for (int k = 0; k < KK; ++k) {
        float fv[4];
        fv[0] = bflo2f(fr0[k].x); fv[1] = bfhi2f(fr0[k].x);
        fv[2] = bflo2f(fr0[k].y); fv[3] = bfhi2f(fr0[k].y);
        const float* pr = &u.s.perm[(p0 * KK + k) * 10];
        float2 q0 = *(const float2*)(pr + 0);
        float2 q1 = *(const float2*)(pr + 2);
        float2 q2 = *(const float2*)(pr + 4);
        float2 q3 = *(const float2*)(pr + 6);
        float pvv[8] = {q0.x, q0.y, q1.x, q1.y, q2.x, q2.y, q3.x, q3.y};
        #pragma unroll
        for (int ci = 0; ci < 4; ++ci)
            #pragma unroll
            for (int m = 0; m < MM; ++m)
                acc0[ci][m] += fv[ci] * pvv[m];
    }
    #pragma unroll
    for (int k = 0; k < KK; ++k) {
        float fv[4];
        fv[0] = bflo2f(fr1[k].x); fv[1] = bfhi2f(fr1[k].x);
        fv[2] = bflo2f(fr1[k].y); fv[3] = bfhi2f(fr1[k].y);
        const float* pr = &u.s.perm[(p1 * KK + k) * 10];
        float2 q0 = *(const float2*)(pr + 0);
        float2 q1 = *(const float2*)(pr + 2);
        float2 q2 = *(const float2*)(pr + 4);
        float2 q3 = *(const float2*)(pr + 6);
        float pvv[8] = {q0.x, q0.y, q1.x, q1.y, q2.x, q2.y, q3.x, q3.y};
        #pragma unroll
        for (int ci = 0; ci < 4; ++ci)
            #pragma unroll
            for (int m = 0; m < MM; ++m)
                acc1[ci][m] += fv[ci] * pvv[m];
    }
    __syncthreads();   // B3: perm dead, safe to overlay with aggA

    #pragma unroll
    for (int ci = 0; ci < 4; ++ci) {
        union { bf16x8 v; unsigned short s2[8]; } pk;
        #pragma unroll
        for (int m = 0; m < MM; ++m) pk.s2[m] = f2bf(acc0[ci][m]);
        *(bf16x8*)&u.aggA[p0 * AST + (cq + ci) * MM] = pk.v;
    }
    #pragma unroll
    for (int ci = 0; ci < 4; ++ci) {
        union { bf16x8 v; unsigned short s2[8]; } pk;
        #pragma unroll
        for (int m = 0; m < MM; ++m) pk.s2[m] = f2bf(acc1[ci][m]);
        *(bf16x8*)&u.aggA[p1 * AST + (cq + ci) * MM] = pk.v;
    }
    __syncthreads();   // B4: aggA ready

    // ---- phase C: two 16x16 point-tiles x 16-o tile per wave, shared B-frags ----
    {
        f32x4 d0 = {0.f, 0.f, 0.f, 0.f};
        f32x4 d1 = {0.f, 0.f, 0.f, 0.f};
        const unsigned short* wrow = Wb + (size_t)o * CM;
        const unsigned short* a0 = u.aggA + (l & 15) * AST;
        const unsigned short* a1 = u.aggA + ((l & 15) + 16) * AST;
        #pragma unroll
        for (int s = 0; s < 16; ++s) {
            int koff = s * 32 + q * 8;
            bf16x8 bB = *(const bf16x8*)&wrow[koff];
            d0 = __builtin_amdgcn_mfma_f32_16x16x32_bf16(*(const bf16x8*)&a0[koff], bB, d0, 0, 0, 0);
            d1 = __builtin_amdgcn_mfma_f32_16x16x32_bf16(*(const bf16x8*)&a1[koff], bB, d1, 0, 0, 0);
        }
        float* op = out + ((size_t)b * CC + o) * NNN + n0;
        float4 r0, r1;
        #pragma unroll
        for (int r = 0; r < 4; ++r) {
            float v0 = d0[r] + bias;
            v0 = v0 > 0.f ? v0 : v0 * 0.2f;
            ((float*)&r0)[r] = v0 + ((const float*)&fres0)[r];
            float v1 = d1[r] + bias;
            v1 = v1 > 0.f ? v1 : v1 * 0.2f;
            ((float*)&r1)[r] = v1 + ((const float*)&fres1)[r];
        }
        *(float4*)(op + q * 4) = r0;
        *(float4*)(op + 16 + q * 4) = r1;
    }
}

extern "C" void kernel_launch(void* const* d_in, const int* in_sizes, int n_in,
                              void* d_out, int out_size, void* d_ws, size_t ws_size,
                              hipStream_t stream) {
    const float* x        = (const float*)d_in[0];
    const float* feature  = (const float*)d_in[1];
    const int*   nidx     = (const int*)d_in[2];
    const float* kern     = (const float*)d_in[3];
    const float* conv_w   = (const float*)d_in[4];
    const float* conv_b   = (const float*)d_in[5];
    float* out = (float*)d_out;

    unsigned short* ftr = (unsigned short*)d_ws;                      // 4 MB: (B,N,C) bf16
    unsigned short* Wb  = (unsigned short*)((char*)d_ws + 4194304);   // 64 KB: bf16 W [o][k]

    prep_kernel<<<516, 256, 0, stream>>>(feature, conv_w, ftr, Wb);
    main_kernel<<<1024, 256, 0, stream>>>(x, feature, nidx, kern, conv_b, ftr, Wb, out);
}

// Round 5
// 110.503 us; speedup vs baseline: 1.0234x; 1.0234x over previous
//
#include <hip/hip_runtime.h>
#include <hip/hip_bf16.h>

#define BB 8
#define CC 64
#define NNN 4096
#define KK 20
#define MM 8
#define OC 64
#define CM 512
#define AST 516                 // aggA row stride in shorts
#define REGB 8352               // per-wave LDS region bytes (multiple of 16)

typedef __attribute__((ext_vector_type(8))) short bf16x8;
typedef __attribute__((ext_vector_type(4))) float f32x4;
typedef __attribute__((ext_vector_type(2))) float f32x2;

__device__ __forceinline__ unsigned short f2bf(float f) {
    union { float f; unsigned int u; } v; v.f = f;
    unsigned int u = v.u;
    return (unsigned short)((u + 0x7FFFu + ((u >> 16) & 1u)) >> 16);
}
__device__ __forceinline__ unsigned int pack2bf(float a, float b) {
    union { __hip_bfloat162 h; unsigned int u; } pk;
    pk.h = __float22bfloat162_rn(make_float2(a, b));
    return pk.u;
}
__device__ __forceinline__ float bfhi2f(unsigned int u) {
    union { unsigned int u; float f; } v; v.u = u & 0xffff0000u; return v.f;
}
__device__ __forceinline__ float bflo2f(unsigned int u) {
    union { unsigned int u; float f; } v; v.u = u << 16; return v.f;
}

// Kernel 1: transpose feature (B,C,N)->(B,N,C) bf16 into ws; conv_w -> bf16 [o][k]
__global__ __launch_bounds__(256) void prep_kernel(const float* __restrict__ feature,
                                                   const float* __restrict__ conv_w,
                                                   unsigned short* __restrict__ ftr,
                                                   unsigned short* __restrict__ Wb) {
    int blk = blockIdx.x;
    int t = threadIdx.x;
    if (blk < 512) {
        __shared__ float tile[64 * 65];
        int b = blk & 7;
        int n0 = (blk >> 3) << 6;
        const float* fb = feature + b * (CC * NNN);
        #pragma unroll
        for (int s = 0; s < 16; ++s) {
            int i = t + s * 256;
            int c = i >> 6, nn = i & 63;
            tile[c * 65 + nn] = fb[c * NNN + n0 + nn];
        }
        __syncthreads();
        unsigned short* fo = ftr + b * (NNN * CC) + n0 * CC;
        #pragma unroll
        for (int s = 0; s < 16; ++s) {
            int i = t + s * 256;
            int n = i >> 6, cc = i & 63;
            fo[n * CC + cc] = f2bf(tile[cc * 65 + n]);
        }
    } else {
        int base = (blk - 512) * 8192;
        #pragma unroll
        for (int s = 0; s < 32; ++s) {
            int i = base + t + s * 256;
            Wb[i] = f2bf(conv_w[i]);
        }
    }
}

// Kernel 2: 16 points/block, 2 waves; each wave owns 8 points through stage->softmax->agg.
__global__ __launch_bounds__(128, 3) void main_kernel(
    const float* __restrict__ x,
    const float* __restrict__ feature,
    const int* __restrict__ nidx,
    const float* __restrict__ kern,
    const float* __restrict__ conv_b,
    const unsigned short* __restrict__ ftr,
    const unsigned short* __restrict__ Wb,
    float* __restrict__ out)
{
    // per-wave region: {xn[480] f32 | perm[8*20*10] f32} overlaid later by aggA (8 rows x 516 shorts)
    __shared__ __align__(16) unsigned char smem[2 * REGB];

    int t = threadIdx.x;
    int w = t >> 6, l = t & 63;
    int blk = blockIdx.x;
    int b = blk & 7;                         // XCD-affinity swizzle
    int n0 = (blk >> 3) << 4;

    float* xnF  = (float*)(smem + w * REGB);         // 480 floats
    float* permF = xnF + 480;                        // 8*20*10 floats

    int p = l >> 3;                          // point-in-wave 0..7
    int m = l & 7;                           // phase A: kernel col; phase B: channel-octet
    int cL = l & 7;

    const int* nb_w = nidx + ((b * NNN + n0 + w * 8)) * KK;   // wave's 8 points
    const float* xb = x + b * (3 * NNN);
    const unsigned short* fbb = ftr + (size_t)b * (NNN * CC);

    // ---- ids for chunks 0,1 + phase-A kernel weights (independent loads first) ----
    const int4* nb4 = (const int4*)(nb_w + p * KK);
    int4 idc0 = nb4[0];
    int4 idc1 = nb4[1];
    float kw0 = kern[m], kw1 = kern[MM + m], kw2 = kern[2 * MM + m];

    // ---- stage wave's 8 points' neighbor xyz into xn (480 floats) ----
    #pragma unroll
    for (int s = 0; s < 8; ++s) {
        int i = l + s * 64;
        if (i < 480) {
            int p2 = i / 60;
            int rem = i - p2 * 60;
            int k = rem / 3;
            int c = rem - k * 3;
            int idv = nb_w[p2 * KK + k];
            xnF[i] = xb[c * NNN + idv];
        }
    }

    // ---- issue ftr gathers for chunk 0 (ids already in flight/landed) ----
    uint4 frA[4], frB[4];
    {
        const int* ic = (const int*)&idc0;
        #pragma unroll
        for (int j = 0; j < 4; ++j)
            frA[j] = *(const uint4*)(fbb + (size_t)ic[j] * CC + cL * 8);
    }
    __syncthreads();   // B1: xn ready

    // ---- phase A: permatrix + softmax over k; lane = (p, m) ----
    {
        const float* xp = xnF + p * 60;
        float pv[KK];
        float bx, by, bz;
        #pragma unroll
        for (int tt = 0; tt < 10; ++tt) {
            f32x2 a = *(const f32x2*)(xp + 6 * tt);
            f32x2 bq = *(const f32x2*)(xp + 6 * tt + 2);
            f32x2 cq = *(const f32x2*)(xp + 6 * tt + 4);
            if (tt == 0) { bx = a.x; by = a.y; bz = bq.x; }
            pv[2 * tt]     = (a.x - bx) * kw0 + (a.y - by) * kw1 + (bq.x - bz) * kw2;
            pv[2 * tt + 1] = (bq.y - bx) * kw0 + (cq.x - by) * kw1 + (cq.y - bz) * kw2;
        }
        if (m == 0) pv[0] += 1.0f;           // one_pad[0,0]
        float mx = pv[0];
        #pragma unroll
        for (int k = 1; k < KK; ++k) mx = fmaxf(mx, pv[k]);
        float sum = 0.f;
        #pragma unroll
        for (int k = 0; k < KK; ++k) { pv[k] = __expf(pv[k] - mx); sum += pv[k]; }
        float inv = 1.0f / sum;
        #pragma unroll
        for (int k = 0; k < KK; ++k) permF[(p * KK + k) * 10 + m] = pv[k] * inv;
    }
    __syncthreads();   // B2: perm ready

    // ---- phase B: acc[c][m] += f[k][c]*perm[k][m]; lane=(p,cL), c = cL*8..cL*8+7 ----
    // 5 chunks of 4 k; prefetch next chunk's gathers; reload ids per chunk (L1-hot).
    f32x2 accp[4][MM];                       // [c-pair][m], packed f32
    #pragma unroll
    for (int cp = 0; cp < 4; ++cp)
        #pragma unroll
        for (int mm2 = 0; mm2 < MM; ++mm2) accp[cp][mm2] = (f32x2){0.f, 0.f};

    int4 idnext = idc1;
    #pragma unroll
    for (int c4 = 0; c4 < 5; ++c4) {
        uint4* cur = (c4 & 1) ? frB : frA;
        uint4* nxt = (c4 & 1) ? frA : frB;
        // prefetch chunk c4+1 gathers
        if (c4 < 4) {
            const int* in_ = (const int*)&idnext;
            #pragma unroll
            for (int j = 0; j < 4; ++j)
                nxt[j] = *(const uint4*)(fbb + (size_t)in_[j] * CC + cL * 8);
        }
        // prefetch ids for chunk c4+2
        if (c4 < 3) idnext = nb4[c4 + 2];
        // compute chunk c4
        #pragma unroll
        for (int j = 0; j < 4; ++j) {
            int k = c4 * 4 + j;
            const float* pr = permF + (p * KK + k) * 10;
            f32x2 pm0 = *(const f32x2*)(pr + 0);
            f32x2 pm1 = *(const f32x2*)(pr + 2);
            f32x2 pm2 = *(const f32x2*)(pr + 4);
            f32x2 pm3 = *(const f32x2*)(pr + 6);
            float pms[8] = {pm0.x, pm0.y, pm1.x, pm1.y, pm2.x, pm2.y, pm3.x, pm3.y};
            const unsigned int* dw = (const unsigned int*)&cur[j];
            f32x2 fvp[4];
            #pragma unroll
            for (int d = 0; d < 4; ++d)
                fvp[d] = (f32x2){bflo2f(dw[d]), bfhi2f(dw[d])};
            #pragma unroll
            for (int mm2 = 0; mm2 < MM; ++mm2) {
                f32x2 pmm = {pms[mm2], pms[mm2]};
                #pragma unroll
                for (int cp = 0; cp < 4; ++cp)
                    accp[cp][mm2] += fvp[cp] * pmm;
            }
        }
    }
    __syncthreads();   // B3: all perm reads complete everywhere; safe to overlay aggA

    // ---- pack acc -> bf16 aggA row (k-order = c*8+m), rows wave-local ----
    {
        unsigned short* aggRow = (unsigned short*)(smem + w * REGB) + p * AST + cL * 8 * MM;
        #pragma unroll
        for (int i = 0; i < 8; ++i) {        // c = cL*8 + i
            int cp = i >> 1;
            unsigned int d0, d1, d2, d3;
            if ((i & 1) == 0) {
                d0 = pack2bf(accp[cp][0].x, accp[cp][1].x);
                d1 = pack2bf(accp[cp][2].x, accp[cp][3].x);
                d2 = pack2bf(accp[cp][4].x, accp[cp][5].x);
                d3 = pack2bf(accp[cp][6].x, accp[cp][7].x);
            } else {
                d0 = pack2bf(accp[cp][0].y, accp[cp][1].y);
                d1 = pack2bf(accp[cp][2].y, accp[cp][3].y);
                d2 = pack2bf(accp[cp][4].y, accp[cp][5].y);
                d3 = pack2bf(accp[cp][6].y, accp[cp][7].y);
            }
            uint2* dst = (uint2*)(aggRow + i * MM);
            dst[0] = make_uint2(d0, d1);
            dst[1] = make_uint2(d2, d3);
        }
    }
    __syncthreads();   // B4: aggA ready (both waves)

    // ---- phase C: 16pts x 32o per wave via MFMA + fused epilogue ----
    {
        int o0 = w * 32 + (l & 15);
        int o1 = o0 + 16;
        int q = l >> 4;
        int rowp = l & 15;
        const unsigned short* arow = (const unsigned short*)(smem + (rowp >> 3) * REGB)
                                     + (rowp & 7) * AST + q * 8;
        const unsigned short* wr0 = Wb + (size_t)o0 * CM + q * 8;
        const unsigned short* wr1 = Wb + (size_t)o1 * CM + q * 8;
        // residual + bias prefetch (latency hides under MFMA loop)
        const float* fbase = feature + (size_t)b * (CC * NNN) + n0 + q * 4;
        float4 res0 = *(const float4*)(fbase + (size_t)o0 * NNN);
        float4 res1 = *(const float4*)(fbase + (size_t)o1 * NNN);
        float bias0 = conv_b[o0], bias1 = conv_b[o1];

        f32x4 d0 = {0.f, 0.f, 0.f, 0.f};
        f32x4 d1 = {0.f, 0.f, 0.f, 0.f};
        #pragma unroll
        for (int s = 0; s < 16; ++s) {
            bf16x8 af = *(const bf16x8*)(arow + s * 32);
            bf16x8 b0 = *(const bf16x8*)(wr0 + s * 32);
            bf16x8 b1 = *(const bf16x8*)(wr1 + s * 32);
            d0 = __builtin_amdgcn_mfma_f32_16x16x32_bf16(af, b0, d0, 0, 0, 0);
            d1 = __builtin_amdgcn_mfma_f32_16x16x32_bf16(af, b1, d1, 0, 0, 0);
        }
        float* ob = out + (size_t)b * (OC * NNN) + n0 + q * 4;
        float4 r0, r1;
        #pragma unroll
        for (int r = 0; r < 4; ++r) {
            float v0 = d0[r] + bias0;
            v0 = v0 > 0.f ? v0 : v0 * 0.2f;
            ((float*)&r0)[r] = v0 + ((const float*)&res0)[r];
            float v1 = d1[r] + bias1;
            v1 = v1 > 0.f ? v1 : v1 * 0.2f;
            ((float*)&r1)[r] = v1 + ((const float*)&res1)[r];
        }
        *(float4*)(ob + (size_t)o0 * NNN) = r0;
        *(float4*)(ob + (size_t)o1 * NNN) = r1;
    }
}

extern "C" void kernel_launch(void* const* d_in, const int* in_sizes, int n_in,
                              void* d_out, int out_size, void* d_ws, size_t ws_size,
                              hipStream_t stream) {
    const float* x        = (const float*)d_in[0];
    const float* feature  = (const float*)d_in[1];
    const int*   nidx     = (const int*)d_in[2];
    const float* kern     = (const float*)d_in[3];
    const float* conv_w   = (const float*)d_in[4];
    const float* conv_b   = (const float*)d_in[5];
    float* out = (float*)d_out;

    unsigned short* ftr = (unsigned short*)d_ws;                      // 4 MB: (B,N,C) bf16
    unsigned short* Wb  = (unsigned short*)((char*)d_ws + 4194304);   // 64 KB: bf16 W [o][k]

    prep_kernel<<<516, 256, 0, stream>>>(feature, conv_w, ftr, Wb);
    main_kernel<<<2048, 128, 0, stream>>>(x, feature, nidx, kern, conv_b, ftr, Wb, out);
}